// Round 1
// baseline (150.871 us; speedup 1.0000x reference)
//
#include <hip/hip_runtime.h>

// bicon_loss R7: restore memory-level parallelism.
// R6 counters: VALUBusy 25%, HBM 20%, Occupancy 31% -> latency-bound, nothing
// saturated. Root cause: VGPR_Count=64 (forced by __launch_bounds__(256,4))
// cannot hold the 25-load burst (100 dest VGPRs), so the compiler sank loads
// next to uses -> ~a dozen serialized full-latency round trips per wave.
// Fix: __launch_bounds__(256,2) (VGPR cap 256) + sched_barrier(0) fence after
// the load phase so all 25 loads are in flight before compute. Trades resident
// waves (8 -> ~4/SIMD) for ~25 outstanding loads/wave: latency-bound -> BW-bound.

#define EPSF 1e-7f

constexpr int B = 16, H = 352, W = 352;
constexpr int HW = H * W;        // 123904
constexpr int N = B * HW;        // 1982464
constexpr int W4 = W / 4;        // 88
constexpr int HW4 = HW / 4;      // 30976
constexpr int NQ = N / 4;        // 495616 = 1936 * 256 exactly
constexpr int NBLK = NQ / 256;   // 1936

typedef float f4 __attribute__((ext_vector_type(4)));
typedef int   i4 __attribute__((ext_vector_type(4)));

__device__ __forceinline__ float rcpf(float x) { return __builtin_amdgcn_rcpf(x); }

__device__ __forceinline__ f4 sigmoid4(f4 x) {
    f4 r;
    r.x = rcpf(1.0f + __expf(-x.x));
    r.y = rcpf(1.0f + __expf(-x.y));
    r.z = rcpf(1.0f + __expf(-x.z));
    r.w = rcpf(1.0f + __expf(-x.w));
    return r;
}
__device__ __forceinline__ f4 max4(f4 a, f4 b) {
    f4 r; r.x=fmaxf(a.x,b.x); r.y=fmaxf(a.y,b.y); r.z=fmaxf(a.z,b.z); r.w=fmaxf(a.w,b.w); return r;
}
__device__ __forceinline__ f4 min4(f4 a, f4 b) {
    f4 r; r.x=fminf(a.x,b.x); r.y=fminf(a.y,b.y); r.z=fminf(a.z,b.z); r.w=fminf(a.w,b.w); return r;
}
__device__ __forceinline__ f4 sel4(i4 q, f4 a, f4 b) {
    f4 r; r.x=q.x?a.x:b.x; r.y=q.y?a.y:b.y; r.z=q.z?a.z:b.z; r.w=q.w?a.w:b.w; return r;
}
__device__ __forceinline__ f4 loadu4(const float* p) {   // 4B-aligned 16B load
    f4 v; __builtin_memcpy(&v, p, sizeof(f4)); return v;
}

__device__ __forceinline__ float finish_pixel(float glo, float pmin, int sc,
                                              float t, float cp, float ba, float bb) {
    const float edge = (sc < 8 && sc > 0) ? 1.0f : 0.0f;
    float dec = glo * (1.0f - edge) + (1.0f - pmin) * edge;
    dec = fminf(fmaxf(dec, EPSF), 1.0f - EPSF);
    const float de = -(t * __logf(dec) + (1.0f - t) * __logf(1.0f - dec));
    return de - 0.8f * __logf(cp) - 0.2f * (__logf(ba) + __logf(bb));
}

__global__ __launch_bounds__(256, 2) void bicon_loss_kernel(
    const float* __restrict__ c_map,    // [B,8,H,W]
    const float* __restrict__ target,   // [B,1,H,W]
    const int*   __restrict__ con,      // [B,8,H,W] in {0,1}
    float* __restrict__ ws)             // [NBLK] partial sums
{
    const int tid = blockIdx.x * blockDim.x + threadIdx.x;   // < NQ exactly
    const int b  = tid / HW4;
    const int rq = tid - b * HW4;
    const int y  = rq / W4;
    const int xq = rq - y * W4;
    const int x0 = xq * 4;

    const float* __restrict__ cm = c_map + (size_t)b * 8 * HW + y * W + x0;
    const int*   __restrict__ cn = con   + (size_t)b * 8 * HW + y * W + x0;

    // ---------- burst load phase: 25 independent 16B loads ----------
    // Ordered to match use order (c first, then per-DIR n/q pairs, t4 last) so
    // the compiler can emit decrementing vmcnt(N) waits instead of vmcnt(0).
    const f4 c0 = *(const f4*)(cm + 0 * HW);
    const f4 c1 = *(const f4*)(cm + 1 * HW);
    const f4 c2 = *(const f4*)(cm + 2 * HW);
    const f4 c3 = *(const f4*)(cm + 3 * HW);
    const f4 c4 = *(const f4*)(cm + 4 * HW);
    const f4 c5 = *(const f4*)(cm + 5 * HW);
    const f4 c6 = *(const f4*)(cm + 6 * HW);
    const f4 c7 = *(const f4*)(cm + 7 * HW);
    // neighbor raw values: dir i reads channel 7-i at (y-DY, x-DX)
    const f4 n0 = loadu4(cm + 7 * HW - 1 * W - 1);   // DX=+1, DY=+1
    const i4 q0 = *(const i4*)(cn + 0 * HW);
    const f4 n1 = *(const f4*)(cm + 6 * HW - 1 * W); // DX=0,  DY=+1
    const i4 q1 = *(const i4*)(cn + 1 * HW);
    const f4 n2 = loadu4(cm + 5 * HW - 1 * W + 1);   // DX=-1, DY=+1
    const i4 q2 = *(const i4*)(cn + 2 * HW);
    const f4 n3 = loadu4(cm + 4 * HW - 1);           // DX=+1, DY=0
    const i4 q3 = *(const i4*)(cn + 3 * HW);
    const f4 n4 = loadu4(cm + 3 * HW + 1);           // DX=-1, DY=0
    const i4 q4 = *(const i4*)(cn + 4 * HW);
    const f4 n5 = loadu4(cm + 2 * HW + 1 * W - 1);   // DX=+1, DY=-1
    const i4 q5 = *(const i4*)(cn + 5 * HW);
    const f4 n6 = *(const f4*)(cm + 1 * HW + 1 * W); // DX=0,  DY=-1
    const i4 q6 = *(const i4*)(cn + 6 * HW);
    const f4 n7 = loadu4(cm + 0 * HW + 1 * W + 1);   // DX=-1, DY=-1
    const i4 q7 = *(const i4*)(cn + 7 * HW);
    const f4 t4 = *(const f4*)(target + (size_t)b * HW + y * W + x0);

    // Fence: no compute may be hoisted above, no load may sink below.
    // Forces all 25 loads to issue (dests live) before the first use -> full MLP.
    __builtin_amdgcn_sched_barrier(0);

    // ---------- compute phase ----------
    const f4 p0 = sigmoid4(c0);
    const f4 p1 = sigmoid4(c1);
    const f4 p2 = sigmoid4(c2);
    const f4 p3 = sigmoid4(c3);
    const f4 p4 = sigmoid4(c4);
    const f4 p5 = sigmoid4(c5);
    const f4 p6 = sigmoid4(c6);
    const f4 p7 = sigmoid4(c7);

    const float lm = (xq == 0)      ? 0.0f : 1.0f;  // left edge  (DX=+1)
    const float rm = (xq == W4 - 1) ? 0.0f : 1.0f;  // right edge (DX=-1)
    const float tm = (y == 0)       ? 0.0f : 1.0f;  // top row    (DY=+1)
    const float bm = (y == H - 1)   ? 0.0f : 1.0f;  // bottom row (DY=-1)

    f4 conprod = {1.f,1.f,1.f,1.f};
    f4 biA     = {1.f,1.f,1.f,1.f};
    f4 biB     = {1.f,1.f,1.f,1.f};
    f4 glo     = {-1e30f,-1e30f,-1e30f,-1e30f};
    f4 pmin    = { 1e30f, 1e30f, 1e30f, 1e30f};

#define DIR(P, Q, NR, DX, RMASK, BI) {                                        \
        f4 s = sigmoid4(NR);                                                  \
        s *= (RMASK);                                                         \
        if ((DX) == 1)  s.x *= lm;                                            \
        if ((DX) == -1) s.w *= rm;                                            \
        const f4 v = (P) * s;                                                 \
        glo  = max4(glo,  v);                                                 \
        pmin = min4(pmin, v);                                                 \
        conprod *= sel4((Q), (P), 1.0f - (P));                                \
        BI *= sel4((Q), max4(v, (f4){EPSF,EPSF,EPSF,EPSF}), 1.0f - v);        \
    }
    DIR(p0, q0, n0,  1, tm, biA)
    DIR(p1, q1, n1,  0, tm, biA)
    DIR(p2, q2, n2, -1, tm, biA)
    DIR(p3, q3, n3,  1, 1.0f, biA)
    DIR(p4, q4, n4, -1, 1.0f, biB)
    DIR(p5, q5, n5,  1, bm, biB)
    DIR(p6, q6, n6,  0, bm, biB)
    DIR(p7, q7, n7, -1, bm, biB)
#undef DIR

    const i4 sc = q0 + q1 + q2 + q3 + q4 + q5 + q6 + q7;

    float part = finish_pixel(glo.x, pmin.x, sc.x, t4.x, conprod.x, biA.x, biB.x)
               + finish_pixel(glo.y, pmin.y, sc.y, t4.y, conprod.y, biA.y, biB.y)
               + finish_pixel(glo.z, pmin.z, sc.z, t4.z, conprod.z, biA.z, biB.z)
               + finish_pixel(glo.w, pmin.w, sc.w, t4.w, conprod.w, biA.w, biB.w);

    // wave64 shuffle reduction
    #pragma unroll
    for (int off = 32; off > 0; off >>= 1)
        part += __shfl_down(part, off, 64);

    __shared__ float wsum[4];
    const int lane = threadIdx.x & 63;
    const int wid  = threadIdx.x >> 6;
    if (lane == 0) wsum[wid] = part;
    __syncthreads();
    if (threadIdx.x == 0) {
        ws[blockIdx.x] = wsum[0] + wsum[1] + wsum[2] + wsum[3];  // plain store
    }
}

// Stage 2: one block sums the NBLK partials and writes the scalar output.
__global__ __launch_bounds__(256) void reduce_partials_kernel(
    const float* __restrict__ ws, float* __restrict__ out)
{
    float s = 0.0f;
    for (int i = threadIdx.x; i < NBLK; i += 256) s += ws[i];
    #pragma unroll
    for (int off = 32; off > 0; off >>= 1)
        s += __shfl_down(s, off, 64);
    __shared__ float wsum[4];
    const int lane = threadIdx.x & 63;
    const int wid  = threadIdx.x >> 6;
    if (lane == 0) wsum[wid] = s;
    __syncthreads();
    if (threadIdx.x == 0) out[0] = wsum[0] + wsum[1] + wsum[2] + wsum[3];
}

extern "C" void kernel_launch(void* const* d_in, const int* in_sizes, int n_in,
                              void* d_out, int out_size, void* d_ws, size_t ws_size,
                              hipStream_t stream) {
    const float* c_map  = (const float*)d_in[0];
    const float* target = (const float*)d_in[1];
    const int*   con    = (const int*)d_in[2];
    float* out = (float*)d_out;
    float* ws  = (float*)d_ws;   // NBLK floats

    bicon_loss_kernel<<<NBLK, 256, 0, stream>>>(c_map, target, con, ws);
    reduce_partials_kernel<<<1, 256, 0, stream>>>(ws, out);
}

// Round 2
// 149.600 us; speedup vs baseline: 1.0085x; 1.0085x over previous
//
#include <hip/hip_runtime.h>

// bicon_loss R8: force the load burst with liveness pins.
// R7 post-mortem: sched_barrier(0) alone was a NULL - VGPR_Count stayed 64,
// proving codegen never changed. Loads are side-effect-free, so IR-level
// sinking moved them past the intrinsic to their uses before the machine
// scheduler ever saw them. Fix: asm volatile("" :: "v"(x)) USE of every
// loaded value right after the burst. A use cannot be hoisted above its def
// and volatile asm is mutually ordered -> all 26 loads must issue before
// compute, ~110+ live VGPRs, real MLP. launch_bounds(256,2) keeps cap at 256.
// Tripwire: if VGPR_Count is still 64, the pin failed; if VGPR ~150 and time
// is flat, the kernel is at a structural BW cap, not latency-bound.

#define EPSF 1e-7f

constexpr int B = 16, H = 352, W = 352;
constexpr int HW = H * W;        // 123904
constexpr int N = B * HW;        // 1982464
constexpr int W4 = W / 4;        // 88
constexpr int HW4 = HW / 4;      // 30976
constexpr int NQ = N / 4;        // 495616 = 1936 * 256 exactly
constexpr int NBLK = NQ / 256;   // 1936

typedef float f4 __attribute__((ext_vector_type(4)));
typedef int   i4 __attribute__((ext_vector_type(4)));

__device__ __forceinline__ float rcpf(float x) { return __builtin_amdgcn_rcpf(x); }

__device__ __forceinline__ void pinf(const f4& v) { asm volatile("" :: "v"(v)); }
__device__ __forceinline__ void pini(const i4& v) { asm volatile("" :: "v"(v)); }

__device__ __forceinline__ f4 sigmoid4(f4 x) {
    f4 r;
    r.x = rcpf(1.0f + __expf(-x.x));
    r.y = rcpf(1.0f + __expf(-x.y));
    r.z = rcpf(1.0f + __expf(-x.z));
    r.w = rcpf(1.0f + __expf(-x.w));
    return r;
}
__device__ __forceinline__ f4 max4(f4 a, f4 b) {
    f4 r; r.x=fmaxf(a.x,b.x); r.y=fmaxf(a.y,b.y); r.z=fmaxf(a.z,b.z); r.w=fmaxf(a.w,b.w); return r;
}
__device__ __forceinline__ f4 min4(f4 a, f4 b) {
    f4 r; r.x=fminf(a.x,b.x); r.y=fminf(a.y,b.y); r.z=fminf(a.z,b.z); r.w=fminf(a.w,b.w); return r;
}
__device__ __forceinline__ f4 sel4(i4 q, f4 a, f4 b) {
    f4 r; r.x=q.x?a.x:b.x; r.y=q.y?a.y:b.y; r.z=q.z?a.z:b.z; r.w=q.w?a.w:b.w; return r;
}
__device__ __forceinline__ f4 loadu4(const float* p) {   // 4B-aligned 16B load
    f4 v; __builtin_memcpy(&v, p, sizeof(f4)); return v;
}

__device__ __forceinline__ float finish_pixel(float glo, float pmin, int sc,
                                              float t, float cp, float ba, float bb) {
    const float edge = (sc < 8 && sc > 0) ? 1.0f : 0.0f;
    float dec = glo * (1.0f - edge) + (1.0f - pmin) * edge;
    dec = fminf(fmaxf(dec, EPSF), 1.0f - EPSF);
    const float de = -(t * __logf(dec) + (1.0f - t) * __logf(1.0f - dec));
    return de - 0.8f * __logf(cp) - 0.2f * (__logf(ba) + __logf(bb));
}

__global__ __launch_bounds__(256, 2) void bicon_loss_kernel(
    const float* __restrict__ c_map,    // [B,8,H,W]
    const float* __restrict__ target,   // [B,1,H,W]
    const int*   __restrict__ con,      // [B,8,H,W] in {0,1}
    float* __restrict__ ws)             // [NBLK] partial sums
{
    const int tid = blockIdx.x * blockDim.x + threadIdx.x;   // < NQ exactly
    const int b  = tid / HW4;
    const int rq = tid - b * HW4;
    const int y  = rq / W4;
    const int xq = rq - y * W4;
    const int x0 = xq * 4;

    const float* __restrict__ cm = c_map + (size_t)b * 8 * HW + y * W + x0;
    const int*   __restrict__ cn = con   + (size_t)b * 8 * HW + y * W + x0;

    // ---------- burst load phase: 26 independent 16B loads ----------
    const f4 c0 = *(const f4*)(cm + 0 * HW);
    const f4 c1 = *(const f4*)(cm + 1 * HW);
    const f4 c2 = *(const f4*)(cm + 2 * HW);
    const f4 c3 = *(const f4*)(cm + 3 * HW);
    const f4 c4 = *(const f4*)(cm + 4 * HW);
    const f4 c5 = *(const f4*)(cm + 5 * HW);
    const f4 c6 = *(const f4*)(cm + 6 * HW);
    const f4 c7 = *(const f4*)(cm + 7 * HW);
    // neighbor raw values: dir i reads channel 7-i at (y-DY, x-DX)
    const f4 n0 = loadu4(cm + 7 * HW - 1 * W - 1);   // DX=+1, DY=+1
    const f4 n1 = *(const f4*)(cm + 6 * HW - 1 * W); // DX=0,  DY=+1
    const f4 n2 = loadu4(cm + 5 * HW - 1 * W + 1);   // DX=-1, DY=+1
    const f4 n3 = loadu4(cm + 4 * HW - 1);           // DX=+1, DY=0
    const f4 n4 = loadu4(cm + 3 * HW + 1);           // DX=-1, DY=0
    const f4 n5 = loadu4(cm + 2 * HW + 1 * W - 1);   // DX=+1, DY=-1
    const f4 n6 = *(const f4*)(cm + 1 * HW + 1 * W); // DX=0,  DY=-1
    const f4 n7 = loadu4(cm + 0 * HW + 1 * W + 1);   // DX=-1, DY=-1
    const i4 q0 = *(const i4*)(cn + 0 * HW);
    const i4 q1 = *(const i4*)(cn + 1 * HW);
    const i4 q2 = *(const i4*)(cn + 2 * HW);
    const i4 q3 = *(const i4*)(cn + 3 * HW);
    const i4 q4 = *(const i4*)(cn + 4 * HW);
    const i4 q5 = *(const i4*)(cn + 5 * HW);
    const i4 q6 = *(const i4*)(cn + 6 * HW);
    const i4 q7 = *(const i4*)(cn + 7 * HW);
    const f4 t4 = *(const f4*)(target + (size_t)b * HW + y * W + x0);

    // Liveness pins: a volatile-asm USE of each value. Loads cannot sink
    // below their use, so all 26 must be issued before this block completes.
    pinf(c0); pinf(c1); pinf(c2); pinf(c3);
    pinf(c4); pinf(c5); pinf(c6); pinf(c7);
    pinf(n0); pinf(n1); pinf(n2); pinf(n3);
    pinf(n4); pinf(n5); pinf(n6); pinf(n7);
    pini(q0); pini(q1); pini(q2); pini(q3);
    pini(q4); pini(q5); pini(q6); pini(q7);
    pinf(t4);
    __builtin_amdgcn_sched_barrier(0);

    // ---------- compute phase ----------
    const f4 p0 = sigmoid4(c0);
    const f4 p1 = sigmoid4(c1);
    const f4 p2 = sigmoid4(c2);
    const f4 p3 = sigmoid4(c3);
    const f4 p4 = sigmoid4(c4);
    const f4 p5 = sigmoid4(c5);
    const f4 p6 = sigmoid4(c6);
    const f4 p7 = sigmoid4(c7);

    const float lm = (xq == 0)      ? 0.0f : 1.0f;  // left edge  (DX=+1)
    const float rm = (xq == W4 - 1) ? 0.0f : 1.0f;  // right edge (DX=-1)
    const float tm = (y == 0)       ? 0.0f : 1.0f;  // top row    (DY=+1)
    const float bm = (y == H - 1)   ? 0.0f : 1.0f;  // bottom row (DY=-1)

    f4 conprod = {1.f,1.f,1.f,1.f};
    f4 biA     = {1.f,1.f,1.f,1.f};
    f4 biB     = {1.f,1.f,1.f,1.f};
    f4 glo     = {-1e30f,-1e30f,-1e30f,-1e30f};
    f4 pmin    = { 1e30f, 1e30f, 1e30f, 1e30f};

#define DIR(P, Q, NR, DX, RMASK, BI) {                                        \
        f4 s = sigmoid4(NR);                                                  \
        s *= (RMASK);                                                         \
        if ((DX) == 1)  s.x *= lm;                                            \
        if ((DX) == -1) s.w *= rm;                                            \
        const f4 v = (P) * s;                                                 \
        glo  = max4(glo,  v);                                                 \
        pmin = min4(pmin, v);                                                 \
        conprod *= sel4((Q), (P), 1.0f - (P));                                \
        BI *= sel4((Q), max4(v, (f4){EPSF,EPSF,EPSF,EPSF}), 1.0f - v);        \
    }
    DIR(p0, q0, n0,  1, tm, biA)
    DIR(p1, q1, n1,  0, tm, biA)
    DIR(p2, q2, n2, -1, tm, biA)
    DIR(p3, q3, n3,  1, 1.0f, biA)
    DIR(p4, q4, n4, -1, 1.0f, biB)
    DIR(p5, q5, n5,  1, bm, biB)
    DIR(p6, q6, n6,  0, bm, biB)
    DIR(p7, q7, n7, -1, bm, biB)
#undef DIR

    const i4 sc = q0 + q1 + q2 + q3 + q4 + q5 + q6 + q7;

    float part = finish_pixel(glo.x, pmin.x, sc.x, t4.x, conprod.x, biA.x, biB.x)
               + finish_pixel(glo.y, pmin.y, sc.y, t4.y, conprod.y, biA.y, biB.y)
               + finish_pixel(glo.z, pmin.z, sc.z, t4.z, conprod.z, biA.z, biB.z)
               + finish_pixel(glo.w, pmin.w, sc.w, t4.w, conprod.w, biA.w, biB.w);

    // wave64 shuffle reduction
    #pragma unroll
    for (int off = 32; off > 0; off >>= 1)
        part += __shfl_down(part, off, 64);

    __shared__ float wsum[4];
    const int lane = threadIdx.x & 63;
    const int wid  = threadIdx.x >> 6;
    if (lane == 0) wsum[wid] = part;
    __syncthreads();
    if (threadIdx.x == 0) {
        ws[blockIdx.x] = wsum[0] + wsum[1] + wsum[2] + wsum[3];  // plain store
    }
}

// Stage 2: one block sums the NBLK partials and writes the scalar output.
__global__ __launch_bounds__(256) void reduce_partials_kernel(
    const float* __restrict__ ws, float* __restrict__ out)
{
    float s = 0.0f;
    for (int i = threadIdx.x; i < NBLK; i += 256) s += ws[i];
    #pragma unroll
    for (int off = 32; off > 0; off >>= 1)
        s += __shfl_down(s, off, 64);
    __shared__ float wsum[4];
    const int lane = threadIdx.x & 63;
    const int wid  = threadIdx.x >> 6;
    if (lane == 0) wsum[wid] = s;
    __syncthreads();
    if (threadIdx.x == 0) out[0] = wsum[0] + wsum[1] + wsum[2] + wsum[3];
}

extern "C" void kernel_launch(void* const* d_in, const int* in_sizes, int n_in,
                              void* d_out, int out_size, void* d_ws, size_t ws_size,
                              hipStream_t stream) {
    const float* c_map  = (const float*)d_in[0];
    const float* target = (const float*)d_in[1];
    const int*   con    = (const int*)d_in[2];
    float* out = (float*)d_out;
    float* ws  = (float*)d_ws;   // NBLK floats

    bicon_loss_kernel<<<NBLK, 256, 0, stream>>>(c_map, target, con, ws);
    reduce_partials_kernel<<<1, 256, 0, stream>>>(ws, out);
}